// Round 6
// baseline (302.867 us; speedup 1.0000x reference)
//
#include <hip/hip_runtime.h>
#include <math.h>

typedef __attribute__((ext_vector_type(4))) float f32x4;
typedef __attribute__((ext_vector_type(8))) short bf16x8;

// Problem constants
#define NB 16
#define NT 2048
#define NMEL 80
#define NPOS 512          // stacked positions per batch
#define EDIM 16
#define NEMB 8192
#define ENCD 512
#define MROWS (NB*511)    // 8176 logit rows
#define MPAD 8192
#define NVT 32            // 8192 / 256 col tiles

__device__ __forceinline__ unsigned short f2bf(float x) {
    union { float f; unsigned u; } v; v.f = x;
    unsigned r = v.u + 0x7fffu + ((v.u >> 16) & 1u);
    return (unsigned short)(r >> 16);
}

__device__ __forceinline__ void gl_lds16(const void* gsrc, void* lds) {
    __builtin_amdgcn_global_load_lds(
        (const __attribute__((address_space(1))) unsigned int*)gsrc,
        (__attribute__((address_space(3))) unsigned int*)lds,
        16, 0, 0);
}

// ---------------- Kernel 1: prep = codes (blocks 0..511) + enc->bf16 (512..1023)
//                  + tno->bf16 transpose (1024..2047). Also zeroes presence/sctrl.
__global__ __launch_bounds__(256) void prep_kernel(
    const float* __restrict__ feats, const float* __restrict__ proj,
    const float* __restrict__ emb, const float* __restrict__ enc,
    const float* __restrict__ tno,
    int* __restrict__ codes, int* __restrict__ presence, int* __restrict__ sctrl,
    unsigned short* __restrict__ encB, unsigned short* __restrict__ tnoT)
{
    __shared__ float embS[512][EDIM + 1];   // codes: col 16 = 0.5*||e||^2
    __shared__ float tileT[32][33];         // tno transpose staging
    const int bid = blockIdx.x;
    const int tid = threadIdx.x;

    if (bid < 512) {
        // ---- codes path ----
        const int lane = tid & 63;
        const int wave = tid >> 6;
        const int gbase = bid * 16 + wave * 4;
        if (bid < 32) presence[bid * 256 + tid] = 0;
        if (bid == 32 && tid < 160) sctrl[tid] = 0;

        float yn[4][EDIM];
        #pragma unroll
        for (int pi = 0; pi < 4; ++pi) {
            const int g = gbase + pi;
            const int b = g >> 9;
            const int i = g & 511;
            float xv[5];
            float s = 0.f, sq = 0.f;
            #pragma unroll
            for (int qq = 0; qq < 5; ++qq) {
                const int d = lane + 64 * qq;
                const int j = d / 80, k = d - j * 80;
                const float v = feats[((b * NT) + (i * 4 + j)) * NMEL + k];
                xv[qq] = v; s += v; sq += v * v;
            }
            for (int m = 1; m < 64; m <<= 1) { s += __shfl_xor(s, m); sq += __shfl_xor(sq, m); }
            const float mean = s * (1.0f / 320.0f);
            const float var  = sq * (1.0f / 320.0f) - mean * mean;
            const float rstd = rsqrtf(var + 1e-6f);
            float acc[EDIM];
            #pragma unroll
            for (int e = 0; e < EDIM; ++e) acc[e] = 0.f;
            #pragma unroll
            for (int qq = 0; qq < 5; ++qq) {
                const int d = lane + 64 * qq;
                const float xn = (xv[qq] - mean) * rstd;
                #pragma unroll
                for (int e = 0; e < EDIM; ++e) acc[e] += xn * proj[d * EDIM + e];
            }
            for (int m = 1; m < 64; m <<= 1) {
                #pragma unroll
                for (int e = 0; e < EDIM; ++e) acc[e] += __shfl_xor(acc[e], m);
            }
            float nsq = 0.f;
            #pragma unroll
            for (int e = 0; e < EDIM; ++e) nsq += acc[e] * acc[e];
            const float inv = 1.0f / (sqrtf(nsq) + 1e-8f);
            #pragma unroll
            for (int e = 0; e < EDIM; ++e) yn[pi][e] = acc[e] * inv;
        }

        float mind[4]; int mini[4];
        #pragma unroll
        for (int pi = 0; pi < 4; ++pi) { mind[pi] = INFINITY; mini[pi] = 0x7fffffff; }

        for (int c = 0; c < 16; ++c) {
            __syncthreads();
            #pragma unroll
            for (int r = 0; r < 32; ++r) {
                const int flat = r * 256 + tid;
                embS[flat >> 4][flat & 15] = emb[c * 8192 + flat];
            }
            __syncthreads();
            #pragma unroll
            for (int rr = 0; rr < 2; ++rr) {
                const int vl = tid * 2 + rr;
                float e2 = 0.f;
                #pragma unroll
                for (int e = 0; e < EDIM; ++e) e2 += embS[vl][e] * embS[vl][e];
                embS[vl][EDIM] = 0.5f * e2;
            }
            __syncthreads();
            #pragma unroll
            for (int qq = 0; qq < 8; ++qq) {
                const int vl = lane + 64 * qq;
                float ev[EDIM];
                #pragma unroll
                for (int e = 0; e < EDIM; ++e) ev[e] = embS[vl][e];
                const float h2 = embS[vl][EDIM];
                const int v = c * 512 + vl;
                #pragma unroll
                for (int pi = 0; pi < 4; ++pi) {
                    float dot = 0.f;
                    #pragma unroll
                    for (int e = 0; e < EDIM; ++e) dot += yn[pi][e] * ev[e];
                    const float sc = h2 - dot;
                    if (sc < mind[pi]) { mind[pi] = sc; mini[pi] = v; }
                }
            }
        }
        for (int m = 1; m < 64; m <<= 1) {
            #pragma unroll
            for (int pi = 0; pi < 4; ++pi) {
                const float ov = __shfl_xor(mind[pi], m);
                const int   oi = __shfl_xor(mini[pi], m);
                if (ov < mind[pi] || (ov == mind[pi] && oi < mini[pi])) { mind[pi] = ov; mini[pi] = oi; }
            }
        }
        if (lane == 0) {
            #pragma unroll
            for (int pi = 0; pi < 4; ++pi) codes[gbase + pi] = mini[pi];
        }
    } else if (bid < 1024) {
        // ---- enc f32 -> encB bf16 [8192][512], padded rows zero ----
        const int bid2 = bid - 512;          // 0..511 -> 16 rows each
        #pragma unroll
        for (int pass = 0; pass < 4; ++pass) {
            const int m = bid2 * 16 + pass * 4 + (tid >> 6);
            const int d = (tid & 63) * 8;
            bf16x8 o;
            if (m < MROWS) {
                const int b = m / 511, t = m - b * 511;
                const float4 f0 = *(const float4*)&enc[((size_t)(b * 512 + t)) * ENCD + d];
                const float4 f1 = *(const float4*)&enc[((size_t)(b * 512 + t)) * ENCD + d + 4];
                o[0] = f2bf(f0.x); o[1] = f2bf(f0.y); o[2] = f2bf(f0.z); o[3] = f2bf(f0.w);
                o[4] = f2bf(f1.x); o[5] = f2bf(f1.y); o[6] = f2bf(f1.z); o[7] = f2bf(f1.w);
            } else {
                o = (bf16x8){0,0,0,0,0,0,0,0};
            }
            *(bf16x8*)&encB[(size_t)m * ENCD + d] = o;
        }
    } else {
        // ---- tno f32 [512][8192] -> tnoT bf16 [8192][512] ----
        const int bid2 = bid - 1024;         // 0..1023 -> 4 tiles each
        const int tx = tid & 31, ty = tid >> 5;   // 32 x 8
        #pragma unroll
        for (int it = 0; it < 4; ++it) {
            const int tile = bid2 * 4 + it;       // 0..4095
            const int n0 = (tile & 255) * 32;
            const int k0 = (tile >> 8) * 32;
            __syncthreads();
            #pragma unroll
            for (int i = 0; i < 4; ++i)
                tileT[ty + 8 * i][tx] = tno[(size_t)(k0 + ty + 8 * i) * NEMB + n0 + tx];
            __syncthreads();
            #pragma unroll
            for (int i = 0; i < 4; ++i)
                tnoT[(size_t)(n0 + ty + 8 * i) * ENCD + k0 + tx] = f2bf(tileT[tx][ty + 8 * i]);
        }
    }
}

// ---------------- Kernel 2: bf16 MFMA GEMM 256x256, BK=64, 8-phase counted-vmcnt ----
// Wave (wrM,wcN) output: rows {qm*128 + wrM*64 + ...}, cols {qn*128 + wcN*32 + ...} —
// interleaved halves so each phase's ds_reads touch ONE LDS half (progressive release).
__global__ __launch_bounds__(512, 2) void logits_mfma(
    const unsigned short* __restrict__ encB, const unsigned short* __restrict__ tnoT,
    const int* __restrict__ codes,
    float* __restrict__ pm, float* __restrict__ ps, int* __restrict__ pidx,
    float* __restrict__ tgtlog)
{
    __shared__ __align__(16) unsigned short lds[2][2][256 * 64];  // [buf][A,B][row][k] = 128 KB

    const int tid  = threadIdx.x;
    const int lane = tid & 63;
    const int wave = tid >> 6;           // 0..7
    const int wrM = wave >> 2;           // 0..1
    const int wcN = wave & 3;            // 0..3
    const int l15 = lane & 15, q = lane >> 4;

    // XCD mapping: each XCD owns 4 mt rows; vt sweeps within.
    const int bid = blockIdx.x;          // 0..1023
    const int xcd = bid & 7;
    const int idx = bid >> 3;
    const int mt  = xcd * 4 + (idx & 3);
    const int vt  = idx >> 2;
    const int m0 = mt * 256, n0 = vt * 256;

    // staging lane constants: row = base + (lane>>3), slot = lane&7; LDS[r][s] = glob chunk s^(r&7)
    const int srow  = lane >> 3;                       // 0..7
    const int sslot = ((lane & 7) ^ (lane >> 3)) * 8;  // pre-swizzled source chunk (elements)

#define STAGE_HT(gptr, rbase, half, T, mat)                                                        \
    {                                                                                              \
        const int r0_ = (half) * 128 + wave * 16;                                                  \
        gl_lds16((gptr) + (size_t)((rbase) + r0_ + srow) * ENCD + (T) * 64 + sslot,                \
                 &lds[(T) & 1][mat][r0_ * 64]);                                                    \
        gl_lds16((gptr) + (size_t)((rbase) + r0_ + 8 + srow) * ENCD + (T) * 64 + sslot,            \
                 &lds[(T) & 1][mat][(r0_ + 8) * 64]);                                              \
    }

    f32x4 acc[8][4];
    #pragma unroll
    for (int i = 0; i < 8; ++i)
        #pragma unroll
        for (int j = 0; j < 4; ++j)
            acc[i][j] = (f32x4){0.f, 0.f, 0.f, 0.f};

    bf16x8 aF[4][2], bF0[2][2], bF1[2][2];

#define RD_A(qm_, buf_)                                                                            \
    _Pragma("unroll") for (int mi = 0; mi < 4; ++mi)                                               \
    _Pragma("unroll") for (int kk = 0; kk < 2; ++kk)                                               \
        aF[mi][kk] = *(const bf16x8*)&lds[buf_][0][((qm_) * 128 + wrM * 64 + mi * 16 + l15) * 64   \
                                                   + (((kk * 4 + q) ^ (l15 & 7)) * 8)];
#define RD_B(dst, qn_, buf_)                                                                       \
    _Pragma("unroll") for (int ni = 0; ni < 2; ++ni)                                               \
    _Pragma("unroll") for (int kk = 0; kk < 2; ++kk)                                               \
        dst[ni][kk] = *(const bf16x8*)&lds[buf_][1][((qn_) * 128 + wcN * 32 + ni * 16 + l15) * 64  \
                                                    + (((kk * 4 + q) ^ (l15 & 7)) * 8)];
#define DO_MFMA(qm_, qn_, BF)                                                                      \
    _Pragma("unroll") for (int kk = 0; kk < 2; ++kk)                                               \
    _Pragma("unroll") for (int mi = 0; mi < 4; ++mi)                                               \
    _Pragma("unroll") for (int ni = 0; ni < 2; ++ni)                                               \
        acc[(qm_) * 4 + mi][(qn_) * 2 + ni] = __builtin_amdgcn_mfma_f32_16x16x32_bf16(             \
            aF[mi][kk], BF[ni][kk], acc[(qm_) * 4 + mi][(qn_) * 2 + ni], 0, 0, 0);

    // Prologue: 7 half-tiles (T0: A0,B0,B1,A1 ; T1: A0,B0,B1), then vmcnt(6)+barrier
    STAGE_HT(encB, m0, 0, 0, 0);
    STAGE_HT(tnoT, n0, 0, 0, 1);
    STAGE_HT(tnoT, n0, 1, 0, 1);
    STAGE_HT(encB, m0, 1, 0, 0);
    STAGE_HT(encB, m0, 0, 1, 0);
    STAGE_HT(tnoT, n0, 0, 1, 1);
    STAGE_HT(tnoT, n0, 1, 1, 1);
    asm volatile("s_waitcnt vmcnt(6)" ::: "memory");
    __builtin_amdgcn_s_barrier();

    // Main: 8 tiles x 4 phases. Phase P≡0:(qm0,qn0) reads A-h0+B-h0; 1:(0,1) reads B-h1;
    // 2:(1,1) reads A-h1; 3:(1,0) no reads. Stage: P≡0→A1(tb+1), 1→A0(tb+2), 2→B0(tb+2), 3→B1(tb+2).
    #pragma unroll
    for (int P = 0; P < 32; ++P) {
        const int tb  = P >> 2;
        const int ph  = P & 3;
        const int buf = tb & 1;
        if (ph == 0) { RD_A(0, buf); RD_B(bF0, 0, buf); }
        else if (ph == 1) { RD_B(bF1, 1, buf); }
        else if (ph == 2) { RD_A(1, buf); }

        if (ph == 0 && tb + 1 <= 7) STAGE_HT(encB, m0, 1, tb + 1, 0);
        if (ph == 1 && tb + 2 <= 7) STAGE_HT(encB, m0, 0, tb + 2, 0);
        if (ph == 2 && tb + 2 <= 7) STAGE_HT(tnoT, n0, 0, tb + 2, 1);
        if (ph == 3 && tb + 2 <= 7) STAGE_HT(tnoT, n0, 1, tb + 2, 1);

        __builtin_amdgcn_s_barrier();
        __builtin_amdgcn_s_setprio(1);
        if (ph == 0)      { DO_MFMA(0, 0, bF0); }
        else if (ph == 1) { DO_MFMA(0, 1, bF1); }
        else if (ph == 2) { DO_MFMA(1, 1, bF1); }
        else              { DO_MFMA(1, 0, bF0); }
        __builtin_amdgcn_s_setprio(0);

        if (ph == 3) {
            if (P < 24)       { asm volatile("s_waitcnt vmcnt(6)" ::: "memory"); }
            else if (P == 27) { asm volatile("s_waitcnt vmcnt(0)" ::: "memory"); }
        }
        __builtin_amdgcn_s_barrier();
    }
#undef STAGE_HT
#undef RD_A
#undef RD_B
#undef DO_MFMA

    // Epilogue: per-row partial max / first-argmax / sumexp over this block's 256 cols.
    __syncthreads();
    float* redM = (float*)&lds[0][0][0];    // [4][256]
    float* redS = redM + 4 * 256;
    int*   redI = (int*)(redS + 4 * 256);

    #pragma unroll
    for (int qm = 0; qm < 2; ++qm) {
        #pragma unroll
        for (int mi = 0; mi < 4; ++mi) {
            #pragma unroll
            for (int r = 0; r < 4; ++r) {
                const int rl = qm * 128 + wrM * 64 + mi * 16 + q * 4 + r;   // local row
                float lm = -INFINITY; int li = 0;
                #pragma unroll
                for (int qn = 0; qn < 2; ++qn) {
                    #pragma unroll
                    for (int ni = 0; ni < 2; ++ni) {
                        const float v = acc[qm * 4 + mi][qn * 2 + ni][r];
                        const int col = qn * 128 + wcN * 32 + ni * 16 + l15;  // ascending
                        if (v > lm) { lm = v; li = col; }
                    }
                }
                #pragma unroll
                for (int mk = 8; mk >= 1; mk >>= 1) {
                    const float ov = __shfl_xor(lm, mk);
                    const int   oi = __shfl_xor(li, mk);
                    if (ov > lm || (ov == lm && oi < li)) { lm = ov; li = oi; }
                }
                float le = 0.f;
                #pragma unroll
                for (int qn = 0; qn < 2; ++qn)
                    #pragma unroll
                    for (int ni = 0; ni < 2; ++ni)
                        le += __expf(acc[qm * 4 + mi][qn * 2 + ni][r] - lm);
                #pragma unroll
                for (int mk = 8; mk >= 1; mk >>= 1) le += __shfl_xor(le, mk);

                if (l15 == 0) { redM[wcN * 256 + rl] = lm; redS[wcN * 256 + rl] = le; redI[wcN * 256 + rl] = li; }

                const int mg = m0 + rl;
                if (mg < MROWS) {
                    const int bb = mg / 511, tt = mg - bb * 511;
                    const int tv = codes[bb * NPOS + tt + 1];
                    const int rel = tv - n0;
                    #pragma unroll
                    for (int qn = 0; qn < 2; ++qn) {
                        #pragma unroll
                        for (int ni = 0; ni < 2; ++ni) {
                            const int base = qn * 128 + wcN * 32 + ni * 16;
                            if (rel >= base && rel < base + 16 && (rel - base) == l15)
                                tgtlog[mg] = acc[qm * 4 + mi][qn * 2 + ni][r];
                        }
                    }
                }
            }
        }
    }
    __syncthreads();
    if (tid < 256) {
        const int rl = tid;
        const int mg = m0 + rl;
        if (mg < MROWS) {
            float gm = -INFINITY; int gi = 0x7fffffff;
            #pragma unroll
            for (int g2 = 0; g2 < 4; ++g2) {
                const float mv = redM[g2 * 256 + rl];
                const int   iv = redI[g2 * 256 + rl];
                if (mv > gm || (mv == gm && iv < gi)) { gm = mv; gi = iv; }
            }
            float S = 0.f;
            #pragma unroll
            for (int g2 = 0; g2 < 4; ++g2) S += redS[g2 * 256 + rl] * __expf(redM[g2 * 256 + rl] - gm);
            pm[(size_t)vt * MPAD + mg]   = gm;
            ps[(size_t)vt * MPAD + mg]   = S;
            pidx[(size_t)vt * MPAD + mg] = n0 + gi;
        }
    }
}

// ---------------- Kernel 3: combine per-row + block reduce + last-block finalize ----------------
__global__ __launch_bounds__(256) void combine_kernel(
    const float* __restrict__ pm, const float* __restrict__ ps,
    const int* __restrict__ pidx, const float* __restrict__ tgtlog,
    const int* __restrict__ codes, const int* __restrict__ lens,
    int* __restrict__ presence, int* __restrict__ sctrl,
    float* __restrict__ out)
{
    float* partials = (float*)(sctrl + 64);   // 32 blocks x 3
    const int tid = threadIdx.x;
    const int g = blockIdx.x * 256 + tid;
    float nll = 0.f, corr = 0.f, mfv = 0.f;
    if (g < MROWS) {
        float gm = -INFINITY; int gi = 0;
        #pragma unroll 8
        for (int nt = 0; nt < NVT; ++nt) {
            const float v = pm[(size_t)nt * MPAD + g];
            if (v > gm) { gm = v; gi = pidx[(size_t)nt * MPAD + g]; }
        }
        float S = 0.f;
        #pragma unroll 8
        for (int nt = 0; nt < NVT; ++nt) S += ps[(size_t)nt * MPAD + g] * __expf(pm[(size_t)nt * MPAD + g] - gm);
        const float lse = gm + logf(S);
        const int b = g / 511, t = g - b * 511;
        const int tv = codes[b * NPOS + t + 1];
        const int L = lens[b];
        const int s = t + 1;
        const bool mf = (s < (L / 4)) && (4 * s + 3 < L);
        if (mf) {
            nll = lse - tgtlog[g];
            corr = (gi == tv) ? 1.f : 0.f;
            mfv = 1.f;
            if (atomicExch(&presence[tv], 1) == 0) atomicAdd(&sctrl[1], 1);
        }
    }
    __shared__ float s0[256], s1[256], s2[256];
    s0[tid] = nll; s1[tid] = corr; s2[tid] = mfv;
    __syncthreads();
    for (int st = 128; st > 0; st >>= 1) {
        if (tid < st) { s0[tid] += s0[tid + st]; s1[tid] += s1[tid + st]; s2[tid] += s2[tid + st]; }
        __syncthreads();
    }
    if (tid == 0) {
        partials[blockIdx.x * 3 + 0] = s0[0];
        partials[blockIdx.x * 3 + 1] = s1[0];
        partials[blockIdx.x * 3 + 2] = s2[0];
        __threadfence();
        const int tk = atomicAdd(&sctrl[0], 1);
        if (tk == 31) {
            float tn = 0.f, tc = 0.f, tm = 0.f;
            for (int i = 0; i < 32; ++i) {
                tn += atomicAdd(&partials[i * 3 + 0], 0.f);
                tc += atomicAdd(&partials[i * 3 + 1], 0.f);
                tm += atomicAdd(&partials[i * 3 + 2], 0.f);
            }
            const float uq = (float)atomicAdd(&sctrl[1], 0);
            out[0] = tn / tm;
            out[1] = tc / tm;
            out[2] = tm;
            out[3] = uq;
        }
    }
}

extern "C" void kernel_launch(void* const* d_in, const int* in_sizes, int n_in,
                              void* d_out, int out_size, void* d_ws, size_t ws_size,
                              hipStream_t stream) {
    const float* feats = (const float*)d_in[0];
    const int*   lens  = (const int*)d_in[1];
    const float* enc   = (const float*)d_in[2];
    const float* proj  = (const float*)d_in[3];
    const float* emb   = (const float*)d_in[4];
    const float* tno   = (const float*)d_in[5];
    float* out = (float*)d_out;

    int* codes          = (int*)d_ws;                        // 8192
    int* presence       = codes + MPAD;                      // 8192
    int* sctrl          = presence + MPAD;                   // 64 ctrl + 96 partials = 160
    float* pm           = (float*)(sctrl + 160);             // 32*8192
    float* ps           = pm + (size_t)NVT * MPAD;           // 32*8192
    int* pidx           = (int*)(ps + (size_t)NVT * MPAD);   // 32*8192
    float* tgtlog       = (float*)(pidx + (size_t)NVT * MPAD); // 8192
    unsigned short* encB = (unsigned short*)(tgtlog + MPAD); // 8192*512
    unsigned short* tnoT = encB + (size_t)MPAD * ENCD;       // 8192*512

    hipLaunchKernelGGL(prep_kernel, dim3(2048), dim3(256), 0, stream,
                       feats, proj, emb, enc, tno, codes, presence, sctrl, encB, tnoT);
    hipLaunchKernelGGL(logits_mfma, dim3(1024), dim3(512), 0, stream, encB, tnoT, codes, pm, ps, pidx, tgtlog);
    hipLaunchKernelGGL(combine_kernel, dim3(32), dim3(256), 0, stream,
                       pm, ps, pidx, tgtlog, codes, lens, presence, sctrl, out);
}